// Round 2
// baseline (8053.939 us; speedup 1.0000x reference)
//
#include <hip/hip_runtime.h>
#include <stdint.h>

// ---------------------------------------------------------------------------
// ODEFunc: relu -> conv3x3(SAME) -> [pool8x8 -> MLP(pruned w1,w2) -> upsample]
//          -> instance_norm
// Identities:
//  * conv feeds ONLY a 4x4 avgpool => fold pool into conv (9 shifted box sums
//    + GEMM over K=2304), 16x fewer FLOPs than the conv
//  * upsample is 4x4 replication => instance norm computed on the 8x8 grid
//  * prune threshold = exact 90th percentile. R1 change: sampled coarse range
//    -> ballot-COMPACT in-window elements (~1M, sequential writes) -> staged
//    exact select on the compacted set. Kills the 98 MB scattered-atomic
//    traffic that made k_exact_hist run at 13% HBM peak.
// ---------------------------------------------------------------------------

typedef float f32x4 __attribute__((ext_vector_type(4)));
typedef __bf16 bf16x8 __attribute__((ext_vector_type(8)));

#define NBATCH 32
#define NCH    256
#define NNODE  16384
#define FEATD  2048
#define KCONV  2304

static constexpr long long NW    = 33554432LL;          // elems in w1 / w2
static constexpr double    POS_D = 0.9 * (double)(NW - 1);
static constexpr int       K0    = (int)POS_D;          // 30198987, frac=0.9

// workspace layout (bytes)
static constexpr size_t OFF_APOOL = 0;                  // 2048*2304*2 bf16
static constexpr size_t OFF_NODES = 9437184;            // 32*16384*2 bf16
static constexpr size_t OFF_HF32  = 10485760;           // 2048*32*4  f32
static constexpr size_t OFF_HB    = 10747904;           // 32*2048*2  bf16
static constexpr size_t OFF_G     = 10878976;           // 16384*32*4 f32
static constexpr size_t OFF_SHIST = 12976128;           // 4096*4
static constexpr size_t OFF_GHIST = 12992512;           // 8192*4
static constexpr size_t OFF_CTRL  = 13025280;           // 2*64
static constexpr size_t OFF_EBUF  = 13025408;           // 8192*4
static constexpr size_t OFF_CBUF  = 13058176;           // rest of ws
static constexpr size_t WS_MIN    = OFF_CBUF + 8ull * 1024 * 1024;  // >=2M keys
static constexpr unsigned CBUF_MAX = 4u * 1024 * 1024;  // cap on compacted keys
static constexpr int EBUF_CAP = 8192;

struct Ctrl {
  unsigned vlo, vhi, shift, below;   // window bit range, count(|w|<vlo)
  unsigned nin, e_lo, e_hi, base_e;  // compacted count, extract range
  unsigned nex, b0, b1, dbg;
  float thr, a, b;
  unsigned pad;
};

__device__ __forceinline__ float prune1(float v, float thr) {
  return fabsf(v) >= thr ? v : 0.0f;
}

// ---------------- percentile pipeline ----------------

// 512 blocks: each reads 1024 contiguous floats (chunked deterministic sample,
// m = 524288), coarse histogram of |w| bit pattern bits 30..19.
__global__ void k_sample_hist(const float* __restrict__ w, unsigned* __restrict__ hist) {
  __shared__ unsigned lh[4096];
  int t = threadIdx.x;
  for (int i = t; i < 4096; i += 256) lh[i] = 0;
  __syncthreads();
  const float4* p = (const float4*)(w + (size_t)blockIdx.x * 65536);
  float4 v = p[t];
  {
    unsigned k;
    k = (__float_as_uint(v.x) & 0x7fffffffu) >> 19; atomicAdd(&lh[k], 1u);
    k = (__float_as_uint(v.y) & 0x7fffffffu) >> 19; atomicAdd(&lh[k], 1u);
    k = (__float_as_uint(v.z) & 0x7fffffffu) >> 19; atomicAdd(&lh[k], 1u);
    k = (__float_as_uint(v.w) & 0x7fffffffu) >> 19; atomicAdd(&lh[k], 1u);
  }
  __syncthreads();
  for (int i = t; i < 4096; i += 256)
    if (lh[i]) atomicAdd(&hist[i], lh[i]);
}

// From the sample histogram pick coarse-bin window [vlo, vhi) guaranteed
// (9+ sigma of rank noise, rounded OUT to bin edges) to contain ranks K0,K0+1.
__global__ void k_range2(const unsigned* __restrict__ hist, Ctrl* __restrict__ c) {
  __shared__ unsigned csum[256];
  __shared__ unsigned pre[256];
  __shared__ unsigned res[2];
  int t = threadIdx.x;
  unsigned loc[16];
  unsigned s = 0;
  for (int i = 0; i < 16; ++i) { loc[i] = hist[t * 16 + i]; s += loc[i]; }
  csum[t] = s;
  __syncthreads();
  if (t == 0) {
    unsigned acc = 0;
    for (int i = 0; i < 256; ++i) { pre[i] = acc; acc += csum[i]; }
  }
  __syncthreads();
  const int m = 524288, qm = 471859, MR = 2000;   // ~9 sigma rank margin
  int targ[2] = { qm - MR, qm + MR };
  for (int k = 0; k < 2; ++k) {
    int r = targ[k];
    if (r < 0) r = 0;
    if (r >= m) r = m - 1;
    if ((int)pre[t] <= r && r < (int)(pre[t] + csum[t])) {
      unsigned acc = pre[t];
      for (int i = 0; i < 16; ++i) {
        acc += loc[i];
        if ((int)acc > r) { res[k] = (unsigned)(t * 16 + i); break; }
      }
    }
  }
  __syncthreads();
  if (t == 0) {
    int lo = (int)res[0];
    int hi = (int)res[1];
    if (hi - lo + 1 > 8) hi = lo + 7;       // safety clamp (never for iid data)
    c->vlo = (unsigned)lo << 19;
    c->vhi = (unsigned)(hi + 1) << 19;      // exclusive
    unsigned span = c->vhi - c->vlo;
    unsigned sh = 0;
    while ((span >> sh) > 8192u) sh++;
    c->shift = sh;
    c->below = 0; c->nin = 0; c->nex = 0;
    c->thr = 0.f;
  }
}

// Full streaming pass: count below-window; ballot-compact in-window keys.
__global__ void k_compact(const float* __restrict__ w, unsigned* __restrict__ cbuf,
                          Ctrl* __restrict__ c, unsigned cap) {
  int t = threadIdx.x, lane = t & 63;
  unsigned vlo = c->vlo, vhi = c->vhi;
  unsigned below = 0;
  const float4* p = (const float4*)(w + (size_t)blockIdx.x * 32768);
  for (int it = 0; it < 32; ++it) {
    float4 v = p[it * 256 + t];
    float comps[4] = { v.x, v.y, v.z, v.w };
#pragma unroll
    for (int j = 0; j < 4; ++j) {
      unsigned key = __float_as_uint(comps[j]) & 0x7fffffffu;
      below += (key < vlo) ? 1u : 0u;
      bool in = (key >= vlo) & (key < vhi);
      unsigned long long msk = __ballot(in);
      if (msk) {
        int leader = __ffsll((unsigned long long)msk) - 1;
        unsigned base = 0;
        if (lane == leader) base = atomicAdd(&c->nin, (unsigned)__popcll(msk));
        base = (unsigned)__shfl((int)base, leader, 64);
        if (in) {
          unsigned prefix = (unsigned)__popcll(msk & ((1ull << lane) - 1ull));
          unsigned idx = base + prefix;
          if (idx < cap) cbuf[idx] = key;
        }
      }
    }
  }
  for (int off = 1; off < 64; off <<= 1) below += __shfl_xor(below, off);
  if (lane == 0) atomicAdd(&c->below, below);
}

// 8192-bin LDS histogram of compacted keys, merged to global.
__global__ void k_sel_hist(const unsigned* __restrict__ cbuf, unsigned* __restrict__ gh,
                           const Ctrl* __restrict__ c, unsigned cap) {
  __shared__ unsigned h[8192];
  int t = threadIdx.x;
  for (int i = t; i < 8192; i += 256) h[i] = 0;
  __syncthreads();
  unsigned vlo = c->vlo, sh = c->shift;
  unsigned n = c->nin; if (n > cap) n = cap;
  for (unsigned i = blockIdx.x * 256 + t; i < n; i += 64 * 256)
    atomicAdd(&h[(cbuf[i] - vlo) >> sh], 1u);
  __syncthreads();
  for (int i = t; i < 8192; i += 256)
    if (h[i]) atomicAdd(&gh[i], h[i]);
}

// Locate bins holding ranks K0, K0+1; define extraction bit range.
__global__ void k_sel_bin(const unsigned* __restrict__ gh, Ctrl* __restrict__ c,
                          unsigned cap) {
  __shared__ unsigned cs[256];
  __shared__ unsigned pre[257];
  __shared__ int bsel[2];
  __shared__ unsigned pbase[2];
  int t = threadIdx.x;
  unsigned loc[32];
  unsigned s = 0;
  for (int i = 0; i < 32; ++i) { loc[i] = gh[t * 32 + i]; s += loc[i]; }
  cs[t] = s;
  __syncthreads();
  if (t == 0) {
    unsigned acc = 0;
    for (int i = 0; i < 256; ++i) { pre[i] = acc; acc += cs[i]; }
    pre[256] = acc;
    bsel[0] = 0; bsel[1] = 0; pbase[0] = 0; pbase[1] = 0;
  }
  __syncthreads();
  long long nin = (long long)(c->nin > cap ? cap : c->nin);
  long long below = (long long)c->below;
  for (int k = 0; k < 2; ++k) {
    long long r = (long long)(K0 + k) - below;
    if (r < 0) r = 0;
    if (r >= nin) r = nin - 1;
    if ((long long)pre[t] <= r && r < (long long)pre[t] + (long long)cs[t]) {
      unsigned acc = pre[t];
      for (int i = 0; i < 32; ++i) {
        if ((long long)(acc + loc[i]) > r) { bsel[k] = t * 32 + i; pbase[k] = acc; break; }
        acc += loc[i];
      }
    }
    __syncthreads();
  }
  if (t == 0) {
    int b0 = bsel[0], b1 = bsel[1];
    c->b0 = (unsigned)b0; c->b1 = (unsigned)b1;
    c->e_lo = c->vlo + ((unsigned)b0 << c->shift);
    c->e_hi = c->vlo + ((unsigned)(b1 + 1) << c->shift);
    c->base_e = c->below + pbase[0];        // count(|w| < e_lo)
    c->nex = 0;
  }
}

// Pull the few hundred candidate keys in [e_lo, e_hi).
__global__ void k_extract(const unsigned* __restrict__ cbuf, unsigned* __restrict__ ebuf,
                          Ctrl* __restrict__ c, unsigned cap) {
  unsigned e_lo = c->e_lo, e_hi = c->e_hi;
  unsigned n = c->nin; if (n > cap) n = cap;
  for (unsigned i = blockIdx.x * 256 + threadIdx.x; i < n; i += 64 * 256) {
    unsigned k = cbuf[i];
    if (k >= e_lo && k < e_hi) {
      unsigned p = atomicAdd(&c->nex, 1u);
      if (p < (unsigned)EBUF_CAP) ebuf[p] = k;
    }
  }
}

// Exact tie-aware selection of a[K0], a[K0+1]; lerp -> threshold.
__global__ void k_final(const unsigned* __restrict__ ebuf, Ctrl* __restrict__ c,
                        double frac) {
  __shared__ unsigned keys[EBUF_CAP];
  __shared__ unsigned abits, bbits;
  int t = threadIdx.x;
  int n = (int)c->nex; if (n > EBUF_CAP) n = EBUF_CAP;
  for (int i = t; i < n; i += 256) keys[i] = ebuf[i];
  if (t == 0) { abits = 0; bbits = 0; }
  __syncthreads();
  long long r0 = (long long)K0 - (long long)c->base_e;
  long long r1 = r0 + 1;
  if (r0 < 0) r0 = 0; if (r0 > n - 1) r0 = n - 1;
  if (r1 < 0) r1 = 0; if (r1 > n - 1) r1 = n - 1;
  for (int i = t; i < n; i += 256) {
    unsigned k = keys[i];
    int cl = 0, ce = 0;
    for (int j = 0; j < n; ++j) {
      cl += (keys[j] < k) ? 1 : 0;
      ce += (keys[j] <= k) ? 1 : 0;
    }
    if ((long long)cl <= r0 && r0 < (long long)ce) abits = k;
    if ((long long)cl <= r1 && r1 < (long long)ce) bbits = k;
  }
  __syncthreads();
  if (t == 0) {
    double a = (double)__uint_as_float(abits);
    double b = (double)__uint_as_float(bbits);
    c->a = (float)a; c->b = (float)b;
    c->thr = (float)(a + frac * (b - a));
  }
}

// ---------------- compute pipeline ----------------

// relu(x) -> nine shifted 4x4 box sums (the pooled conv taps), bf16 out.
__global__ void k_pool(const float* __restrict__ x, __bf16* __restrict__ apool) {
  __shared__ float lds[4][1024];
  __shared__ float V[4][24][32];
  int t = threadIdx.x, wv = t >> 6, lane = t & 63;
  int p = blockIdx.x * 4 + wv;          // plane id: b*256 + c'
  int b = p >> 8, cch = p & 255;
  const float* xp = x + (size_t)p * 1024;
  for (int q = 0; q < 4; ++q) {
    float4 v = ((const float4*)xp)[q * 64 + lane];
    int idx = (q * 64 + lane) * 4;
    lds[wv][idx + 0] = fmaxf(v.x, 0.f);
    lds[wv][idx + 1] = fmaxf(v.y, 0.f);
    lds[wv][idx + 2] = fmaxf(v.z, 0.f);
    lds[wv][idx + 3] = fmaxf(v.w, 0.f);
  }
  __syncthreads();
  for (int e = lane; e < 768; e += 64) {
    int vi = e >> 5, ccol = e & 31;
    int i = vi / 3, dy = vi % 3;
    int r0 = 4 * i + dy - 1;
    float s = 0.f;
#pragma unroll
    for (int u = 0; u < 4; ++u) {
      int r = r0 + u;
      if (r >= 0 && r < 32) s += lds[wv][r * 32 + ccol];
    }
    V[wv][vi][ccol] = s;
  }
  __syncthreads();
  int pos = lane, i = pos >> 3, j = pos & 7;
  __bf16* ap = apool + (size_t)(b * 64 + pos) * KCONV + cch * 9;
#pragma unroll
  for (int dy = 0; dy < 3; ++dy) {
    int vi = i * 3 + dy;
#pragma unroll
    for (int dx = 0; dx < 3; ++dx) {
      int c0 = 4 * j + dx - 1;
      float s = 0.f;
#pragma unroll
      for (int v4 = 0; v4 < 4; ++v4) {
        int cc = c0 + v4;
        if (cc >= 0 && cc < 32) s += V[wv][vi][cc];
      }
      ap[dy * 3 + dx] = (__bf16)(s * 0.0625f);
    }
  }
}

// pooled conv as GEMM: nodes[b, c*64+pos] = sum_K conv_w[c,K] * apool[row,K]
__global__ void k_convgemm(const __bf16* __restrict__ apool, const float* __restrict__ cw,
                           __bf16* __restrict__ nodes) {
  int t = threadIdx.x, wv = t >> 6, l = t & 63;
  int cb = blockIdx.x & 15;        // 16-channel tile
  int rg = blockIdx.x >> 4;        // 256-row group
  int row0 = rg * 256 + wv * 64;
  int cbase = cb * 16;
  int kofs = (l >> 4) * 8;
  f32x4 acc[4] = {};
  const float* aw = cw + (size_t)(cbase + (l & 15)) * KCONV + kofs;
  for (int kk = 0; kk < KCONV; kk += 32) {
    float4 a0 = *(const float4*)(aw + kk);
    float4 a1 = *(const float4*)(aw + kk + 4);
    bf16x8 af;
    af[0] = (__bf16)a0.x; af[1] = (__bf16)a0.y; af[2] = (__bf16)a0.z; af[3] = (__bf16)a0.w;
    af[4] = (__bf16)a1.x; af[5] = (__bf16)a1.y; af[6] = (__bf16)a1.z; af[7] = (__bf16)a1.w;
#pragma unroll
    for (int rt = 0; rt < 4; ++rt) {
      const __bf16* bp = apool + (size_t)(row0 + rt * 16 + (l & 15)) * KCONV + kk + kofs;
      bf16x8 bv = *(const bf16x8*)bp;
      acc[rt] = __builtin_amdgcn_mfma_f32_16x16x32_bf16(af, bv, acc[rt], 0, 0, 0);
    }
  }
#pragma unroll
  for (int rt = 0; rt < 4; ++rt) {
    int prow = row0 + rt * 16 + (l & 15);
    int bidx = prow >> 6, pos = prow & 63;
#pragma unroll
    for (int j = 0; j < 4; ++j) {
      int cc = cbase + (l >> 4) * 4 + j;
      nodes[(size_t)bidx * NNODE + cc * 64 + pos] = (__bf16)acc[rt][j];
    }
  }
}

// h_partial[f, b] += sum_k prune(w1[f,k]) * nodes[b,k];  K split 32 ways.
__global__ void k_gemm1(const float* __restrict__ w1, const __bf16* __restrict__ nodes,
                        const Ctrl* __restrict__ ctrl, float* __restrict__ hf) {
  int t = threadIdx.x, wv = t >> 6, l = t & 63;
  int fb = blockIdx.x >> 5;        // 32 feature blocks of 64
  int ks = blockIdx.x & 31;        // K chunk of 512
  float thr = ctrl->thr;
  int kofs = (l >> 4) * 8;
  int kk0 = ks * 512;
  const float*  awp = w1 + (size_t)(fb * 64 + wv * 16 + (l & 15)) * NNODE + kk0 + kofs;
  const __bf16* b0p = nodes + (size_t)(l & 15) * NNODE + kk0 + kofs;
  const __bf16* b1p = nodes + (size_t)((l & 15) + 16) * NNODE + kk0 + kofs;
  f32x4 acc0 = {}, acc1 = {};
#pragma unroll 4
  for (int kk = 0; kk < 512; kk += 32) {
    float4 a0 = *(const float4*)(awp + kk);
    float4 a1 = *(const float4*)(awp + kk + 4);
    bf16x8 af;
    af[0] = (__bf16)prune1(a0.x, thr); af[1] = (__bf16)prune1(a0.y, thr);
    af[2] = (__bf16)prune1(a0.z, thr); af[3] = (__bf16)prune1(a0.w, thr);
    af[4] = (__bf16)prune1(a1.x, thr); af[5] = (__bf16)prune1(a1.y, thr);
    af[6] = (__bf16)prune1(a1.z, thr); af[7] = (__bf16)prune1(a1.w, thr);
    bf16x8 bv0 = *(const bf16x8*)(b0p + kk);
    bf16x8 bv1 = *(const bf16x8*)(b1p + kk);
    acc0 = __builtin_amdgcn_mfma_f32_16x16x32_bf16(af, bv0, acc0, 0, 0, 0);
    acc1 = __builtin_amdgcn_mfma_f32_16x16x32_bf16(af, bv1, acc1, 0, 0, 0);
  }
#pragma unroll
  for (int j = 0; j < 4; ++j) {
    int f = fb * 64 + wv * 16 + (l >> 4) * 4 + j;
    atomicAdd(&hf[f * 32 + (l & 15)], acc0[j]);
    atomicAdd(&hf[f * 32 + 16 + (l & 15)], acc1[j]);
  }
}

// relu + transpose + bf16 for GEMM2's B operand
__global__ void k_relucvt(const float* __restrict__ hf, __bf16* __restrict__ hb) {
  int idx = blockIdx.x * 256 + threadIdx.x;   // 65536
  float v = fmaxf(hf[idx], 0.f);
  int f = idx >> 5, b = idx & 31;
  hb[b * FEATD + f] = (__bf16)v;
}

// g[n, b] += sum_f prune(w2[n,f]) * h[b,f];  K split 4 ways.
__global__ void k_gemm2(const float* __restrict__ w2, const __bf16* __restrict__ hb,
                        const Ctrl* __restrict__ ctrl, float* __restrict__ g) {
  int t = threadIdx.x, wv = t >> 6, l = t & 63;
  int nb = blockIdx.x >> 2;        // 256 row blocks of 64
  int ks = blockIdx.x & 3;         // K chunk of 512
  float thr = ctrl->thr;
  int kofs = (l >> 4) * 8;
  int kk0 = ks * 512;
  const float*  awp = w2 + (size_t)(nb * 64 + wv * 16 + (l & 15)) * FEATD + kk0 + kofs;
  const __bf16* b0p = hb + (size_t)(l & 15) * FEATD + kk0 + kofs;
  const __bf16* b1p = hb + (size_t)((l & 15) + 16) * FEATD + kk0 + kofs;
  f32x4 acc0 = {}, acc1 = {};
#pragma unroll 4
  for (int kk = 0; kk < 512; kk += 32) {
    float4 a0 = *(const float4*)(awp + kk);
    float4 a1 = *(const float4*)(awp + kk + 4);
    bf16x8 af;
    af[0] = (__bf16)prune1(a0.x, thr); af[1] = (__bf16)prune1(a0.y, thr);
    af[2] = (__bf16)prune1(a0.z, thr); af[3] = (__bf16)prune1(a0.w, thr);
    af[4] = (__bf16)prune1(a1.x, thr); af[5] = (__bf16)prune1(a1.y, thr);
    af[6] = (__bf16)prune1(a1.z, thr); af[7] = (__bf16)prune1(a1.w, thr);
    bf16x8 bv0 = *(const bf16x8*)(b0p + kk);
    bf16x8 bv1 = *(const bf16x8*)(b1p + kk);
    acc0 = __builtin_amdgcn_mfma_f32_16x16x32_bf16(af, bv0, acc0, 0, 0, 0);
    acc1 = __builtin_amdgcn_mfma_f32_16x16x32_bf16(af, bv1, acc1, 0, 0, 0);
  }
#pragma unroll
  for (int j = 0; j < 4; ++j) {
    int n = nb * 64 + wv * 16 + (l >> 4) * 4 + j;
    atomicAdd(&g[n * 32 + (l & 15)], acc0[j]);
    atomicAdd(&g[n * 32 + 16 + (l & 15)], acc1[j]);
  }
}

// instance norm on the 8x8 grid (== norm of the upsampled map) + 4x upsample
__global__ void k_normup(const float* __restrict__ g, const float* __restrict__ gamma,
                         const float* __restrict__ beta, float* __restrict__ out) {
  int t = threadIdx.x, wv = t >> 6, lane = t & 63;
  int id = blockIdx.x * 4 + wv;         // b*256 + c
  int b = id >> 8, cch = id & 255;
  float v = g[(size_t)(cch * 64 + lane) * 32 + b];
  float s = v;
  for (int off = 1; off < 64; off <<= 1) s += __shfl_xor(s, off);
  float mean = s * (1.0f / 64.0f);
  float d = v - mean;
  float q = d * d;
  for (int off = 1; off < 64; off <<= 1) q += __shfl_xor(q, off);
  float var = q * (1.0f / 64.0f);
  float y = d * rsqrtf(var + 1e-5f) * gamma[cch] + beta[cch];
  int i = lane >> 3, j = lane & 7;
  float4 y4 = { y, y, y, y };
  float* op = out + ((size_t)(b * 256 + cch) * 32 + i * 4) * 32 + j * 4;
#pragma unroll
  for (int u = 0; u < 4; ++u) *(float4*)(op + u * 32) = y4;
}

// ---------------------------------------------------------------------------

extern "C" void kernel_launch(void* const* d_in, const int* in_sizes, int n_in,
                              void* d_out, int out_size, void* d_ws, size_t ws_size,
                              hipStream_t stream) {
  const float* x      = (const float*)d_in[0];
  const float* conv_w = (const float*)d_in[1];
  const float* w1     = (const float*)d_in[2];
  const float* w2     = (const float*)d_in[3];
  const float* gamma  = (const float*)d_in[4];
  const float* beta   = (const float*)d_in[5];
  float* out = (float*)d_out;

  if (ws_size < WS_MIN) return;   // fail loudly via wrong output

  char* wsb = (char*)d_ws;
  __bf16*   apool = (__bf16*)(wsb + OFF_APOOL);
  __bf16*   nodes = (__bf16*)(wsb + OFF_NODES);
  float*    hf    = (float*)(wsb + OFF_HF32);
  __bf16*   hb    = (__bf16*)(wsb + OFF_HB);
  float*    g     = (float*)(wsb + OFF_G);
  unsigned* shist = (unsigned*)(wsb + OFF_SHIST);
  unsigned* ghist = (unsigned*)(wsb + OFF_GHIST);
  Ctrl*     ctrl  = (Ctrl*)(wsb + OFF_CTRL);
  unsigned* ebuf  = (unsigned*)(wsb + OFF_EBUF);
  unsigned* cbuf  = (unsigned*)(wsb + OFF_CBUF);

  unsigned cap = (unsigned)((ws_size - OFF_CBUF) / 4);
  if (cap > CBUF_MAX) cap = CBUF_MAX;

  const double frac = POS_D - (double)K0;
  const float* wm[2] = { w1, w2 };
  for (int m = 0; m < 2; ++m) {
    Ctrl* c = ctrl + m;
    hipMemsetAsync(shist, 0, 4096 * 4, stream);
    hipMemsetAsync(ghist, 0, 8192 * 4, stream);
    k_sample_hist<<<512, 256, 0, stream>>>(wm[m], shist);
    k_range2<<<1, 256, 0, stream>>>(shist, c);
    k_compact<<<1024, 256, 0, stream>>>(wm[m], cbuf, c, cap);
    k_sel_hist<<<64, 256, 0, stream>>>(cbuf, ghist, c, cap);
    k_sel_bin<<<1, 256, 0, stream>>>(ghist, c, cap);
    k_extract<<<64, 256, 0, stream>>>(cbuf, ebuf, c, cap);
    k_final<<<1, 256, 0, stream>>>(ebuf, c, frac);
  }

  k_pool<<<2048, 256, 0, stream>>>(x, apool);
  k_convgemm<<<128, 256, 0, stream>>>(apool, conv_w, nodes);

  hipMemsetAsync(hf, 0, 2048 * 32 * 4, stream);
  k_gemm1<<<1024, 256, 0, stream>>>(w1, nodes, ctrl + 0, hf);
  k_relucvt<<<256, 256, 0, stream>>>(hf, hb);

  hipMemsetAsync(g, 0, 16384 * 32 * 4, stream);
  k_gemm2<<<1024, 256, 0, stream>>>(w2, hb, ctrl + 1, g);

  k_normup<<<2048, 256, 0, stream>>>(g, gamma, beta, out);
}

// Round 5
// 636.278 us; speedup vs baseline: 12.6579x; 12.6579x over previous
//
#include <hip/hip_runtime.h>
#include <stdint.h>

// ---------------------------------------------------------------------------
// ODEFunc: relu -> conv3x3(SAME) -> [pool8x8 -> MLP(pruned w1,w2) -> upsample]
//          -> instance_norm
// Identities:
//  * conv feeds ONLY a 4x4 avgpool => fold pool into conv (9 shifted box sums
//    + GEMM over K=2304), 16x fewer FLOPs than the conv
//  * upsample is 4x4 replication => instance norm computed on the 8x8 grid
//  * prune threshold = exact 90th percentile: sampled coarse window ->
//    LDS-staged compaction into fixed per-wave segments (R2 fix: ZERO
//    hot-path device atomics; the single-address atomicAdd per ballot was
//    serializing at ~100K/s and cost 4.2 ms) -> staged exact select.
// ---------------------------------------------------------------------------

typedef float f32x4 __attribute__((ext_vector_type(4)));
typedef __bf16 bf16x8 __attribute__((ext_vector_type(8)));

#define NBATCH 32
#define NCH    256
#define NNODE  16384
#define FEATD  2048
#define KCONV  2304

static constexpr long long NW    = 33554432LL;          // elems in w1 / w2
static constexpr double    POS_D = 0.9 * (double)(NW - 1);
static constexpr int       K0    = (int)POS_D;          // 30198987, frac=0.9

static constexpr int WAVE_CAP = 768;    // staged keys per wave-segment
static constexpr int NSEG     = 4096;   // 1024 blocks x 4 waves
static constexpr int OVCAP    = 65536;  // overflow keys (cold path)
static constexpr int EBUF_CAP = 8192;

// workspace layout (bytes)
static constexpr size_t OFF_APOOL = 0;                  // 2048*2304*2 bf16
static constexpr size_t OFF_NODES = 9437184;            // 32*16384*2 bf16
static constexpr size_t OFF_HF32  = 10485760;           // 2048*32*4  f32
static constexpr size_t OFF_HB    = 10747904;           // 32*2048*2  bf16
static constexpr size_t OFF_G     = 10878976;           // 16384*32*4 f32
static constexpr size_t OFF_SHIST = 12976128;           // 4096*4
static constexpr size_t OFF_GHIST = 12992512;           // 8192*4
static constexpr size_t OFF_CTRL  = 13025280;           // 2*64
static constexpr size_t OFF_EBUF  = 13025408;           // 8192*4
static constexpr size_t OFF_CNT   = 13058176;           // 4096*4
static constexpr size_t OFF_BLW   = 13074560;           // 4096*4
static constexpr size_t OFF_CBUF  = 13090944;           // NSEG*WAVE_CAP*4
static constexpr size_t OFF_OVF   = OFF_CBUF + (size_t)NSEG * WAVE_CAP * 4;
static constexpr size_t WS_MIN    = OFF_OVF + (size_t)OVCAP * 4;   // ~24.8 MB

struct Ctrl {
  unsigned vlo, vhi, shift, nov;
  unsigned e_lo, e_hi, base_e, nex;
  unsigned b0, b1, dbg, pad;
  float thr, a, b;
  unsigned pad2;
};

__device__ __forceinline__ float prune1(float v, float thr) {
  return fabsf(v) >= thr ? v : 0.0f;
}

// ---------------- percentile pipeline ----------------

// 512 blocks: each reads 1024 contiguous floats (chunked deterministic sample,
// m = 524288), coarse histogram of |w| bit pattern bits 30..19.
__global__ void k_sample_hist(const float* __restrict__ w, unsigned* __restrict__ hist) {
  __shared__ unsigned lh[4096];
  int t = threadIdx.x;
  for (int i = t; i < 4096; i += 256) lh[i] = 0;
  __syncthreads();
  const float4* p = (const float4*)(w + (size_t)blockIdx.x * 65536);
  float4 v = p[t];
  {
    unsigned k;
    k = (__float_as_uint(v.x) & 0x7fffffffu) >> 19; atomicAdd(&lh[k], 1u);
    k = (__float_as_uint(v.y) & 0x7fffffffu) >> 19; atomicAdd(&lh[k], 1u);
    k = (__float_as_uint(v.z) & 0x7fffffffu) >> 19; atomicAdd(&lh[k], 1u);
    k = (__float_as_uint(v.w) & 0x7fffffffu) >> 19; atomicAdd(&lh[k], 1u);
  }
  __syncthreads();
  for (int i = t; i < 4096; i += 256)
    if (lh[i]) atomicAdd(&hist[i], lh[i]);
}

// From the sample histogram pick coarse-bin window [vlo, vhi) guaranteed
// (9+ sigma of rank noise, rounded OUT to bin edges) to contain ranks K0,K0+1.
__global__ void k_range2(const unsigned* __restrict__ hist, Ctrl* __restrict__ c) {
  __shared__ unsigned csum[256];
  __shared__ unsigned pre[256];
  __shared__ unsigned res[2];
  int t = threadIdx.x;
  unsigned loc[16];
  unsigned s = 0;
  for (int i = 0; i < 16; ++i) { loc[i] = hist[t * 16 + i]; s += loc[i]; }
  csum[t] = s;
  __syncthreads();
  if (t == 0) {
    unsigned acc = 0;
    for (int i = 0; i < 256; ++i) { pre[i] = acc; acc += csum[i]; }
  }
  __syncthreads();
  const int m = 524288, qm = 471859, MR = 2000;   // ~9 sigma rank margin
  int targ[2] = { qm - MR, qm + MR };
  for (int k = 0; k < 2; ++k) {
    int r = targ[k];
    if (r < 0) r = 0;
    if (r >= m) r = m - 1;
    if ((int)pre[t] <= r && r < (int)(pre[t] + csum[t])) {
      unsigned acc = pre[t];
      for (int i = 0; i < 16; ++i) {
        acc += loc[i];
        if ((int)acc > r) { res[k] = (unsigned)(t * 16 + i); break; }
      }
    }
  }
  __syncthreads();
  if (t == 0) {
    int lo = (int)res[0];
    int hi = (int)res[1];
    if (hi - lo + 1 > 8) hi = lo + 7;       // safety clamp (never for iid data)
    c->vlo = (unsigned)lo << 19;
    c->vhi = (unsigned)(hi + 1) << 19;      // exclusive
    unsigned span = c->vhi - c->vlo;
    unsigned sh = 0;
    while ((span >> sh) > 8192u) sh++;
    c->shift = sh;
    c->nov = 0; c->nex = 0;
    c->thr = 0.f;
  }
}

// Full streaming pass. Per-wave LDS staging, fixed per-wave output segments,
// plain stores for counts -- no hot-path atomics at all.
__global__ void k_compact(const float* __restrict__ w, unsigned* __restrict__ cbuf,
                          unsigned* __restrict__ ovf, unsigned* __restrict__ counts,
                          unsigned* __restrict__ belows, Ctrl* __restrict__ c) {
  __shared__ unsigned lbuf[4][WAVE_CAP];
  int t = threadIdx.x, wv = t >> 6, lane = t & 63;
  unsigned vlo = c->vlo, vhi = c->vhi;
  unsigned below = 0;
  unsigned cnt = 0;                       // wave-uniform staged count
  unsigned long long lanemask = (1ull << lane) - 1ull;
  const float4* p = (const float4*)(w + (size_t)blockIdx.x * 32768);
  for (int it = 0; it < 32; ++it) {
    float4 v = p[it * 256 + t];
    float comps[4] = { v.x, v.y, v.z, v.w };
#pragma unroll
    for (int j = 0; j < 4; ++j) {
      unsigned key = __float_as_uint(comps[j]) & 0x7fffffffu;
      below += (key < vlo) ? 1u : 0u;
      bool in = (key >= vlo) && (key < vhi);
      unsigned long long msk = __ballot(in);
      if (in) {
        unsigned slot = cnt + (unsigned)__popcll(msk & lanemask);
        if (slot < (unsigned)WAVE_CAP) lbuf[wv][slot] = key;
        else {                            // cold spill (>23 sigma)
          unsigned ps = atomicAdd(&c->nov, 1u);
          if (ps < (unsigned)OVCAP) ovf[ps] = key;
        }
      }
      cnt += (unsigned)__popcll(msk);
    }
  }
  for (int off = 1; off < 64; off <<= 1) below += __shfl_xor(below, off);
  unsigned staged = cnt < (unsigned)WAVE_CAP ? cnt : (unsigned)WAVE_CAP;
  int s = blockIdx.x * 4 + wv;
  unsigned* dst = cbuf + (size_t)s * WAVE_CAP;
  for (unsigned i = lane; i < staged; i += 64) dst[i] = lbuf[wv][i];
  if (lane == 0) { counts[s] = staged; belows[s] = below; }
}

// 8192-bin LDS histogram over all segments + overflow, merged to global.
__global__ void k_sel_hist(const unsigned* __restrict__ cbuf, const unsigned* __restrict__ ovf,
                           const unsigned* __restrict__ counts, unsigned* __restrict__ gh,
                           const Ctrl* __restrict__ c) {
  __shared__ unsigned h[8192];
  int t = threadIdx.x;
  for (int i = t; i < 8192; i += 256) h[i] = 0;
  __syncthreads();
  unsigned vlo = c->vlo, sh = c->shift;
  for (int i = 0; i < 64; ++i) {
    int s = blockIdx.x * 64 + i;
    unsigned n = counts[s];
    const unsigned* seg = cbuf + (size_t)s * WAVE_CAP;
    for (unsigned k = t; k < n; k += 256)
      atomicAdd(&h[(seg[k] - vlo) >> sh], 1u);
  }
  if (blockIdx.x == 0) {
    unsigned nov = c->nov; if (nov > (unsigned)OVCAP) nov = OVCAP;
    for (unsigned k = t; k < nov; k += 256)
      atomicAdd(&h[(ovf[k] - vlo) >> sh], 1u);
  }
  __syncthreads();
  for (int i = t; i < 8192; i += 256)
    if (h[i]) atomicAdd(&gh[i], h[i]);
}

// Locate bins holding ranks K0, K0+1; define extraction bit range.
__global__ void k_sel_bin(const unsigned* __restrict__ gh, const unsigned* __restrict__ counts,
                          const unsigned* __restrict__ belows, Ctrl* __restrict__ c) {
  __shared__ unsigned rb[256], rc[256];
  __shared__ unsigned cs[256];
  __shared__ unsigned pre[257];
  __shared__ int bsel[2];
  __shared__ unsigned pbase[2];
  __shared__ long long tot_below, tot_nin;
  int t = threadIdx.x;
  unsigned bsum = 0, csum2 = 0;
  for (int i = 0; i < 16; ++i) { bsum += belows[t * 16 + i]; csum2 += counts[t * 16 + i]; }
  rb[t] = bsum; rc[t] = csum2;
  unsigned loc[32];
  unsigned s = 0;
  for (int i = 0; i < 32; ++i) { loc[i] = gh[t * 32 + i]; s += loc[i]; }
  cs[t] = s;
  __syncthreads();
  if (t == 0) {
    unsigned acc = 0;
    for (int i = 0; i < 256; ++i) { pre[i] = acc; acc += cs[i]; }
    pre[256] = acc;
    long long a = 0, b = 0;
    for (int i = 0; i < 256; ++i) { a += rb[i]; b += rc[i]; }
    unsigned nov = c->nov; if (nov > (unsigned)OVCAP) nov = OVCAP;
    tot_below = a; tot_nin = b + nov;
    bsel[0] = 0; bsel[1] = 0; pbase[0] = 0; pbase[1] = 0;
  }
  __syncthreads();
  long long nin = tot_nin;
  long long below = tot_below;
  for (int k = 0; k < 2; ++k) {
    long long r = (long long)(K0 + k) - below;
    if (r < 0) r = 0;
    if (r >= nin) r = nin - 1;
    if ((long long)pre[t] <= r && r < (long long)pre[t] + (long long)cs[t]) {
      unsigned acc = pre[t];
      for (int i = 0; i < 32; ++i) {
        if ((long long)(acc + loc[i]) > r) { bsel[k] = t * 32 + i; pbase[k] = acc; break; }
        acc += loc[i];
      }
    }
    __syncthreads();
  }
  if (t == 0) {
    int b0 = bsel[0], b1 = bsel[1];
    c->b0 = (unsigned)b0; c->b1 = (unsigned)b1;
    c->e_lo = c->vlo + ((unsigned)b0 << c->shift);
    c->e_hi = c->vlo + ((unsigned)(b1 + 1) << c->shift);
    c->base_e = (unsigned)(below + (long long)pbase[0]);  // count(|w| < e_lo)
    c->nex = 0;
  }
}

// Pull the few hundred candidate keys in [e_lo, e_hi).
__global__ void k_extract(const unsigned* __restrict__ cbuf, const unsigned* __restrict__ ovf,
                          const unsigned* __restrict__ counts, unsigned* __restrict__ ebuf,
                          Ctrl* __restrict__ c) {
  unsigned e_lo = c->e_lo, e_hi = c->e_hi;
  int t = threadIdx.x;
  for (int i = 0; i < 64; ++i) {
    int s = blockIdx.x * 64 + i;
    unsigned n = counts[s];
    const unsigned* seg = cbuf + (size_t)s * WAVE_CAP;
    for (unsigned k = t; k < n; k += 256) {
      unsigned key = seg[k];
      if (key >= e_lo && key < e_hi) {
        unsigned p = atomicAdd(&c->nex, 1u);
        if (p < (unsigned)EBUF_CAP) ebuf[p] = key;
      }
    }
  }
  if (blockIdx.x == 0) {
    unsigned nov = c->nov; if (nov > (unsigned)OVCAP) nov = OVCAP;
    for (unsigned k = t; k < nov; k += 256) {
      unsigned key = ovf[k];
      if (key >= e_lo && key < e_hi) {
        unsigned p = atomicAdd(&c->nex, 1u);
        if (p < (unsigned)EBUF_CAP) ebuf[p] = key;
      }
    }
  }
}

// Exact tie-aware selection of a[K0], a[K0+1]; lerp -> threshold.
__global__ void k_final(const unsigned* __restrict__ ebuf, Ctrl* __restrict__ c,
                        double frac) {
  __shared__ unsigned keys[EBUF_CAP];
  __shared__ unsigned abits, bbits;
  int t = threadIdx.x;
  int n = (int)c->nex; if (n > EBUF_CAP) n = EBUF_CAP;
  for (int i = t; i < n; i += 256) keys[i] = ebuf[i];
  if (t == 0) { abits = 0; bbits = 0; }
  __syncthreads();
  long long r0 = (long long)K0 - (long long)c->base_e;
  long long r1 = r0 + 1;
  if (r0 < 0) r0 = 0; if (r0 > n - 1) r0 = n - 1;
  if (r1 < 0) r1 = 0; if (r1 > n - 1) r1 = n - 1;
  for (int i = t; i < n; i += 256) {
    unsigned k = keys[i];
    int cl = 0, ce = 0;
    for (int j = 0; j < n; ++j) {
      cl += (keys[j] < k) ? 1 : 0;
      ce += (keys[j] <= k) ? 1 : 0;
    }
    if ((long long)cl <= r0 && r0 < (long long)ce) abits = k;
    if ((long long)cl <= r1 && r1 < (long long)ce) bbits = k;
  }
  __syncthreads();
  if (t == 0) {
    double a = (double)__uint_as_float(abits);
    double b = (double)__uint_as_float(bbits);
    c->a = (float)a; c->b = (float)b;
    c->thr = (float)(a + frac * (b - a));
  }
}

// ---------------- compute pipeline ----------------

// relu(x) -> nine shifted 4x4 box sums (the pooled conv taps), bf16 out.
__global__ void k_pool(const float* __restrict__ x, __bf16* __restrict__ apool) {
  __shared__ float lds[4][1024];
  __shared__ float V[4][24][32];
  int t = threadIdx.x, wv = t >> 6, lane = t & 63;
  int p = blockIdx.x * 4 + wv;          // plane id: b*256 + c'
  int b = p >> 8, cch = p & 255;
  const float* xp = x + (size_t)p * 1024;
  for (int q = 0; q < 4; ++q) {
    float4 v = ((const float4*)xp)[q * 64 + lane];
    int idx = (q * 64 + lane) * 4;
    lds[wv][idx + 0] = fmaxf(v.x, 0.f);
    lds[wv][idx + 1] = fmaxf(v.y, 0.f);
    lds[wv][idx + 2] = fmaxf(v.z, 0.f);
    lds[wv][idx + 3] = fmaxf(v.w, 0.f);
  }
  __syncthreads();
  for (int e = lane; e < 768; e += 64) {
    int vi = e >> 5, ccol = e & 31;
    int i = vi / 3, dy = vi % 3;
    int r0 = 4 * i + dy - 1;
    float s = 0.f;
#pragma unroll
    for (int u = 0; u < 4; ++u) {
      int r = r0 + u;
      if (r >= 0 && r < 32) s += lds[wv][r * 32 + ccol];
    }
    V[wv][vi][ccol] = s;
  }
  __syncthreads();
  int pos = lane, i = pos >> 3, j = pos & 7;
  __bf16* ap = apool + (size_t)(b * 64 + pos) * KCONV + cch * 9;
#pragma unroll
  for (int dy = 0; dy < 3; ++dy) {
    int vi = i * 3 + dy;
#pragma unroll
    for (int dx = 0; dx < 3; ++dx) {
      int c0 = 4 * j + dx - 1;
      float s = 0.f;
#pragma unroll
      for (int v4 = 0; v4 < 4; ++v4) {
        int cc = c0 + v4;
        if (cc >= 0 && cc < 32) s += V[wv][vi][cc];
      }
      ap[dy * 3 + dx] = (__bf16)(s * 0.0625f);
    }
  }
}

// pooled conv as GEMM: nodes[b, c*64+pos] = sum_K conv_w[c,K] * apool[row,K]
__global__ void k_convgemm(const __bf16* __restrict__ apool, const float* __restrict__ cw,
                           __bf16* __restrict__ nodes) {
  int t = threadIdx.x, wv = t >> 6, l = t & 63;
  int cb = blockIdx.x & 15;        // 16-channel tile
  int rg = blockIdx.x >> 4;        // 256-row group
  int row0 = rg * 256 + wv * 64;
  int cbase = cb * 16;
  int kofs = (l >> 4) * 8;
  f32x4 acc[4] = {};
  const float* aw = cw + (size_t)(cbase + (l & 15)) * KCONV + kofs;
  for (int kk = 0; kk < KCONV; kk += 32) {
    float4 a0 = *(const float4*)(aw + kk);
    float4 a1 = *(const float4*)(aw + kk + 4);
    bf16x8 af;
    af[0] = (__bf16)a0.x; af[1] = (__bf16)a0.y; af[2] = (__bf16)a0.z; af[3] = (__bf16)a0.w;
    af[4] = (__bf16)a1.x; af[5] = (__bf16)a1.y; af[6] = (__bf16)a1.z; af[7] = (__bf16)a1.w;
#pragma unroll
    for (int rt = 0; rt < 4; ++rt) {
      const __bf16* bp = apool + (size_t)(row0 + rt * 16 + (l & 15)) * KCONV + kk + kofs;
      bf16x8 bv = *(const bf16x8*)bp;
      acc[rt] = __builtin_amdgcn_mfma_f32_16x16x32_bf16(af, bv, acc[rt], 0, 0, 0);
    }
  }
#pragma unroll
  for (int rt = 0; rt < 4; ++rt) {
    int prow = row0 + rt * 16 + (l & 15);
    int bidx = prow >> 6, pos = prow & 63;
#pragma unroll
    for (int j = 0; j < 4; ++j) {
      int cc = cbase + (l >> 4) * 4 + j;
      nodes[(size_t)bidx * NNODE + cc * 64 + pos] = (__bf16)acc[rt][j];
    }
  }
}

// h_partial[f, b] += sum_k prune(w1[f,k]) * nodes[b,k];  K split 32 ways.
__global__ void k_gemm1(const float* __restrict__ w1, const __bf16* __restrict__ nodes,
                        const Ctrl* __restrict__ ctrl, float* __restrict__ hf) {
  int t = threadIdx.x, wv = t >> 6, l = t & 63;
  int fb = blockIdx.x >> 5;        // 32 feature blocks of 64
  int ks = blockIdx.x & 31;        // K chunk of 512
  float thr = ctrl->thr;
  int kofs = (l >> 4) * 8;
  int kk0 = ks * 512;
  const float*  awp = w1 + (size_t)(fb * 64 + wv * 16 + (l & 15)) * NNODE + kk0 + kofs;
  const __bf16* b0p = nodes + (size_t)(l & 15) * NNODE + kk0 + kofs;
  const __bf16* b1p = nodes + (size_t)((l & 15) + 16) * NNODE + kk0 + kofs;
  f32x4 acc0 = {}, acc1 = {};
#pragma unroll 4
  for (int kk = 0; kk < 512; kk += 32) {
    float4 a0 = *(const float4*)(awp + kk);
    float4 a1 = *(const float4*)(awp + kk + 4);
    bf16x8 af;
    af[0] = (__bf16)prune1(a0.x, thr); af[1] = (__bf16)prune1(a0.y, thr);
    af[2] = (__bf16)prune1(a0.z, thr); af[3] = (__bf16)prune1(a0.w, thr);
    af[4] = (__bf16)prune1(a1.x, thr); af[5] = (__bf16)prune1(a1.y, thr);
    af[6] = (__bf16)prune1(a1.z, thr); af[7] = (__bf16)prune1(a1.w, thr);
    bf16x8 bv0 = *(const bf16x8*)(b0p + kk);
    bf16x8 bv1 = *(const bf16x8*)(b1p + kk);
    acc0 = __builtin_amdgcn_mfma_f32_16x16x32_bf16(af, bv0, acc0, 0, 0, 0);
    acc1 = __builtin_amdgcn_mfma_f32_16x16x32_bf16(af, bv1, acc1, 0, 0, 0);
  }
#pragma unroll
  for (int j = 0; j < 4; ++j) {
    int f = fb * 64 + wv * 16 + (l >> 4) * 4 + j;
    atomicAdd(&hf[f * 32 + (l & 15)], acc0[j]);
    atomicAdd(&hf[f * 32 + 16 + (l & 15)], acc1[j]);
  }
}

// relu + transpose + bf16 for GEMM2's B operand
__global__ void k_relucvt(const float* __restrict__ hf, __bf16* __restrict__ hb) {
  int idx = blockIdx.x * 256 + threadIdx.x;   // 65536
  float v = fmaxf(hf[idx], 0.f);
  int f = idx >> 5, b = idx & 31;
  hb[b * FEATD + f] = (__bf16)v;
}

// g[n, b] += sum_f prune(w2[n,f]) * h[b,f];  K split 4 ways.
__global__ void k_gemm2(const float* __restrict__ w2, const __bf16* __restrict__ hb,
                        const Ctrl* __restrict__ ctrl, float* __restrict__ g) {
  int t = threadIdx.x, wv = t >> 6, l = t & 63;
  int nb = blockIdx.x >> 2;        // 256 row blocks of 64
  int ks = blockIdx.x & 3;         // K chunk of 512
  float thr = ctrl->thr;
  int kofs = (l >> 4) * 8;
  int kk0 = ks * 512;
  const float*  awp = w2 + (size_t)(nb * 64 + wv * 16 + (l & 15)) * FEATD + kk0 + kofs;
  const __bf16* b0p = hb + (size_t)(l & 15) * FEATD + kk0 + kofs;
  const __bf16* b1p = hb + (size_t)((l & 15) + 16) * FEATD + kk0 + kofs;
  f32x4 acc0 = {}, acc1 = {};
#pragma unroll 4
  for (int kk = 0; kk < 512; kk += 32) {
    float4 a0 = *(const float4*)(awp + kk);
    float4 a1 = *(const float4*)(awp + kk + 4);
    bf16x8 af;
    af[0] = (__bf16)prune1(a0.x, thr); af[1] = (__bf16)prune1(a0.y, thr);
    af[2] = (__bf16)prune1(a0.z, thr); af[3] = (__bf16)prune1(a0.w, thr);
    af[4] = (__bf16)prune1(a1.x, thr); af[5] = (__bf16)prune1(a1.y, thr);
    af[6] = (__bf16)prune1(a1.z, thr); af[7] = (__bf16)prune1(a1.w, thr);
    bf16x8 bv0 = *(const bf16x8*)(b0p + kk);
    bf16x8 bv1 = *(const bf16x8*)(b1p + kk);
    acc0 = __builtin_amdgcn_mfma_f32_16x16x32_bf16(af, bv0, acc0, 0, 0, 0);
    acc1 = __builtin_amdgcn_mfma_f32_16x16x32_bf16(af, bv1, acc1, 0, 0, 0);
  }
#pragma unroll
  for (int j = 0; j < 4; ++j) {
    int n = nb * 64 + wv * 16 + (l >> 4) * 4 + j;
    atomicAdd(&g[n * 32 + (l & 15)], acc0[j]);
    atomicAdd(&g[n * 32 + 16 + (l & 15)], acc1[j]);
  }
}

// instance norm on the 8x8 grid (== norm of the upsampled map) + 4x upsample
__global__ void k_normup(const float* __restrict__ g, const float* __restrict__ gamma,
                         const float* __restrict__ beta, float* __restrict__ out) {
  int t = threadIdx.x, wv = t >> 6, lane = t & 63;
  int id = blockIdx.x * 4 + wv;         // b*256 + c
  int b = id >> 8, cch = id & 255;
  float v = g[(size_t)(cch * 64 + lane) * 32 + b];
  float s = v;
  for (int off = 1; off < 64; off <<= 1) s += __shfl_xor(s, off);
  float mean = s * (1.0f / 64.0f);
  float d = v - mean;
  float q = d * d;
  for (int off = 1; off < 64; off <<= 1) q += __shfl_xor(q, off);
  float var = q * (1.0f / 64.0f);
  float y = d * rsqrtf(var + 1e-5f) * gamma[cch] + beta[cch];
  int i = lane >> 3, j = lane & 7;
  float4 y4 = { y, y, y, y };
  float* op = out + ((size_t)(b * 256 + cch) * 32 + i * 4) * 32 + j * 4;
#pragma unroll
  for (int u = 0; u < 4; ++u) *(float4*)(op + u * 32) = y4;
}

// ---------------------------------------------------------------------------

extern "C" void kernel_launch(void* const* d_in, const int* in_sizes, int n_in,
                              void* d_out, int out_size, void* d_ws, size_t ws_size,
                              hipStream_t stream) {
  const float* x      = (const float*)d_in[0];
  const float* conv_w = (const float*)d_in[1];
  const float* w1     = (const float*)d_in[2];
  const float* w2     = (const float*)d_in[3];
  const float* gamma  = (const float*)d_in[4];
  const float* beta   = (const float*)d_in[5];
  float* out = (float*)d_out;

  if (ws_size < WS_MIN) return;   // fail loudly via wrong output

  char* wsb = (char*)d_ws;
  __bf16*   apool  = (__bf16*)(wsb + OFF_APOOL);
  __bf16*   nodes  = (__bf16*)(wsb + OFF_NODES);
  float*    hf     = (float*)(wsb + OFF_HF32);
  __bf16*   hb     = (__bf16*)(wsb + OFF_HB);
  float*    g      = (float*)(wsb + OFF_G);
  unsigned* shist  = (unsigned*)(wsb + OFF_SHIST);
  unsigned* ghist  = (unsigned*)(wsb + OFF_GHIST);
  Ctrl*     ctrl   = (Ctrl*)(wsb + OFF_CTRL);
  unsigned* ebuf   = (unsigned*)(wsb + OFF_EBUF);
  unsigned* counts = (unsigned*)(wsb + OFF_CNT);
  unsigned* belows = (unsigned*)(wsb + OFF_BLW);
  unsigned* cbuf   = (unsigned*)(wsb + OFF_CBUF);
  unsigned* ovf    = (unsigned*)(wsb + OFF_OVF);

  const double frac = POS_D - (double)K0;
  const float* wm[2] = { w1, w2 };
  for (int m = 0; m < 2; ++m) {
    Ctrl* c = ctrl + m;
    hipMemsetAsync(shist, 0, 4096 * 4, stream);
    hipMemsetAsync(ghist, 0, 8192 * 4, stream);
    k_sample_hist<<<512, 256, 0, stream>>>(wm[m], shist);
    k_range2<<<1, 256, 0, stream>>>(shist, c);
    k_compact<<<1024, 256, 0, stream>>>(wm[m], cbuf, ovf, counts, belows, c);
    k_sel_hist<<<64, 256, 0, stream>>>(cbuf, ovf, counts, ghist, c);
    k_sel_bin<<<1, 256, 0, stream>>>(ghist, counts, belows, c);
    k_extract<<<64, 256, 0, stream>>>(cbuf, ovf, counts, ebuf, c);
    k_final<<<1, 256, 0, stream>>>(ebuf, c, frac);
  }

  k_pool<<<2048, 256, 0, stream>>>(x, apool);
  k_convgemm<<<128, 256, 0, stream>>>(apool, conv_w, nodes);

  hipMemsetAsync(hf, 0, 2048 * 32 * 4, stream);
  k_gemm1<<<1024, 256, 0, stream>>>(w1, nodes, ctrl + 0, hf);
  k_relucvt<<<256, 256, 0, stream>>>(hf, hb);

  hipMemsetAsync(g, 0, 16384 * 32 * 4, stream);
  k_gemm2<<<1024, 256, 0, stream>>>(w2, hb, ctrl + 1, g);

  k_normup<<<2048, 256, 0, stream>>>(g, gamma, beta, out);
}

// Round 8
// 554.156 us; speedup vs baseline: 14.5337x; 1.1482x over previous
//
#include <hip/hip_runtime.h>
#include <stdint.h>

// ---------------------------------------------------------------------------
// ODEFunc: relu -> conv3x3(SAME) -> [pool8x8 -> MLP(pruned w1,w2) -> upsample]
//          -> instance_norm
// Identities:
//  * conv feeds ONLY a 4x4 avgpool => fold pool into conv (9 shifted box sums
//    + GEMM over K=2304), 16x fewer FLOPs than the conv
//  * upsample is 4x4 replication => instance norm computed on the 8x8 grid
//  * prune threshold = exact 90th percentile: sampled coarse window ->
//    LDS-staged compaction (zero hot-path device atomics, R2 lesson) ->
//    staged exact select. R5: both matrices batched through ONE pipeline
//    (blockIdx.y = matrix), GEMM outputs via K-split partials + plain stores
//    (no device atomics), reductions folded into relucvt/normup.
// ---------------------------------------------------------------------------

typedef float f32x4 __attribute__((ext_vector_type(4)));
typedef __bf16 bf16x8 __attribute__((ext_vector_type(8)));

#define NBATCH 32
#define NCH    256
#define NNODE  16384
#define FEATD  2048
#define KCONV  2304

static constexpr long long NW    = 33554432LL;          // elems in w1 / w2
static constexpr double    POS_D = 0.9 * (double)(NW - 1);
static constexpr int       K0    = (int)POS_D;          // 30198987, frac=0.9

static constexpr int WAVE_CAP = 768;    // staged keys per wave-segment
static constexpr int NSEG     = 4096;   // 1024 blocks x 4 waves
static constexpr int OVCAP    = 65536;  // overflow keys (cold path)
static constexpr int EBUF_CAP = 8192;

// workspace layout (bytes)
static constexpr size_t OFF_APOOL = 0;                   // 2048*2304*2
static constexpr size_t OFF_NODES = 9437184;             // 32*16384*2
static constexpr size_t OFF_HFP   = 10485760;            // 32*65536*4 partials
static constexpr size_t OFF_HB    = 18874368;            // 32*2048*2
static constexpr size_t OFF_GP    = 19005440;            // 4*524288*4 partials
static constexpr size_t OFF_SHIST = 27394048;            // 2*4096*4
static constexpr size_t OFF_GHIST = 27426816;            // 2*8192*4
static constexpr size_t OFF_CTRL  = 27492352;            // 2*64
static constexpr size_t OFF_EBUF  = 27492480;            // 2*8192*4
static constexpr size_t OFF_CNT   = 27558016;            // 2*4096*4
static constexpr size_t OFF_BLW   = 27590784;            // 2*4096*4
static constexpr size_t OFF_CBUF  = 27623552;            // 2*NSEG*WAVE_CAP*4
static constexpr size_t OFF_OVF   = 52789376;            // 2*OVCAP*4
static constexpr size_t WS_MIN    = 53313664;

struct Ctrl {
  unsigned vlo, vhi, shift, nov;
  unsigned e_lo, e_hi, base_e, nex;
  unsigned b0, b1, dbg, pad;
  float thr, a, b;
  unsigned pad2;
};

__device__ __forceinline__ float prune1(float v, float thr) {
  return fabsf(v) >= thr ? v : 0.0f;
}

// ---------------- percentile pipeline (both matrices, blockIdx.y = m) -------

__global__ void k_sample_hist(const float* __restrict__ w1, const float* __restrict__ w2,
                              unsigned* __restrict__ hist) {
  __shared__ unsigned lh[4096];
  int t = threadIdx.x, m = blockIdx.y;
  const float* w = m ? w2 : w1;
  unsigned* gh = hist + m * 4096;
  for (int i = t; i < 4096; i += 256) lh[i] = 0;
  __syncthreads();
  const float4* p = (const float4*)(w + (size_t)blockIdx.x * 65536);
  float4 v = p[t];
  {
    unsigned k;
    k = (__float_as_uint(v.x) & 0x7fffffffu) >> 19; atomicAdd(&lh[k], 1u);
    k = (__float_as_uint(v.y) & 0x7fffffffu) >> 19; atomicAdd(&lh[k], 1u);
    k = (__float_as_uint(v.z) & 0x7fffffffu) >> 19; atomicAdd(&lh[k], 1u);
    k = (__float_as_uint(v.w) & 0x7fffffffu) >> 19; atomicAdd(&lh[k], 1u);
  }
  __syncthreads();
  for (int i = t; i < 4096; i += 256)
    if (lh[i]) atomicAdd(&gh[i], lh[i]);
}

// coarse-bin window [vlo, vhi) guaranteed (9+ sigma, rounded out to bin edges)
__global__ void k_range2(const unsigned* __restrict__ hist, Ctrl* __restrict__ ctrl) {
  __shared__ unsigned csum[256];
  __shared__ unsigned pre[256];
  __shared__ unsigned res[2];
  int t = threadIdx.x, m = blockIdx.x;
  const unsigned* gh = hist + m * 4096;
  Ctrl* c = ctrl + m;
  unsigned loc[16];
  unsigned s = 0;
  for (int i = 0; i < 16; ++i) { loc[i] = gh[t * 16 + i]; s += loc[i]; }
  csum[t] = s;
  __syncthreads();
  if (t == 0) {
    unsigned acc = 0;
    for (int i = 0; i < 256; ++i) { pre[i] = acc; acc += csum[i]; }
  }
  __syncthreads();
  const int msz = 524288, qm = 471859, MR = 2000;   // ~9 sigma rank margin
  int targ[2] = { qm - MR, qm + MR };
  for (int k = 0; k < 2; ++k) {
    int r = targ[k];
    if (r < 0) r = 0;
    if (r >= msz) r = msz - 1;
    if ((int)pre[t] <= r && r < (int)(pre[t] + csum[t])) {
      unsigned acc = pre[t];
      for (int i = 0; i < 16; ++i) {
        acc += loc[i];
        if ((int)acc > r) { res[k] = (unsigned)(t * 16 + i); break; }
      }
    }
  }
  __syncthreads();
  if (t == 0) {
    int lo = (int)res[0];
    int hi = (int)res[1];
    if (hi - lo + 1 > 8) hi = lo + 7;       // safety clamp
    c->vlo = (unsigned)lo << 19;
    c->vhi = (unsigned)(hi + 1) << 19;
    unsigned span = c->vhi - c->vlo;
    unsigned sh = 0;
    while ((span >> sh) > 8192u) sh++;
    c->shift = sh;
    c->nov = 0; c->nex = 0;
    c->thr = 0.f;
  }
}

// Full streaming pass. Per-wave LDS staging, fixed per-wave segments.
__global__ void k_compact(const float* __restrict__ w1, const float* __restrict__ w2,
                          unsigned* __restrict__ cbuf_all, unsigned* __restrict__ ovf_all,
                          unsigned* __restrict__ counts_all, unsigned* __restrict__ belows_all,
                          Ctrl* __restrict__ ctrl) {
  __shared__ unsigned lbuf[4][WAVE_CAP];
  int t = threadIdx.x, wv = t >> 6, lane = t & 63;
  int m = blockIdx.y;
  const float* w = m ? w2 : w1;
  unsigned* cbuf = cbuf_all + (size_t)m * NSEG * WAVE_CAP;
  unsigned* ovf = ovf_all + (size_t)m * OVCAP;
  unsigned* counts = counts_all + m * NSEG;
  unsigned* belows = belows_all + m * NSEG;
  Ctrl* c = ctrl + m;
  unsigned vlo = c->vlo, vhi = c->vhi;
  unsigned below = 0;
  unsigned cnt = 0;
  unsigned long long lanemask = (1ull << lane) - 1ull;
  const float4* p = (const float4*)(w + (size_t)blockIdx.x * 32768);
  for (int it = 0; it < 32; ++it) {
    float4 v = p[it * 256 + t];
    float comps[4] = { v.x, v.y, v.z, v.w };
#pragma unroll
    for (int j = 0; j < 4; ++j) {
      unsigned key = __float_as_uint(comps[j]) & 0x7fffffffu;
      below += (key < vlo) ? 1u : 0u;
      bool in = (key >= vlo) && (key < vhi);
      unsigned long long msk = __ballot(in);
      if (in) {
        unsigned slot = cnt + (unsigned)__popcll(msk & lanemask);
        if (slot < (unsigned)WAVE_CAP) lbuf[wv][slot] = key;
        else {                            // cold spill (>23 sigma)
          unsigned ps = atomicAdd(&c->nov, 1u);
          if (ps < (unsigned)OVCAP) ovf[ps] = key;
        }
      }
      cnt += (unsigned)__popcll(msk);
    }
  }
  for (int off = 1; off < 64; off <<= 1) below += __shfl_xor(below, off);
  unsigned staged = cnt < (unsigned)WAVE_CAP ? cnt : (unsigned)WAVE_CAP;
  int s = blockIdx.x * 4 + wv;
  unsigned* dst = cbuf + (size_t)s * WAVE_CAP;
  for (unsigned i = lane; i < staged; i += 64) dst[i] = lbuf[wv][i];
  if (lane == 0) { counts[s] = staged; belows[s] = below; }
}

__global__ void k_sel_hist(const unsigned* __restrict__ cbuf_all, const unsigned* __restrict__ ovf_all,
                           const unsigned* __restrict__ counts_all, unsigned* __restrict__ gh_all,
                           const Ctrl* __restrict__ ctrl) {
  __shared__ unsigned h[8192];
  int t = threadIdx.x, m = blockIdx.y;
  const unsigned* cbuf = cbuf_all + (size_t)m * NSEG * WAVE_CAP;
  const unsigned* ovf = ovf_all + (size_t)m * OVCAP;
  const unsigned* counts = counts_all + m * NSEG;
  unsigned* gh = gh_all + m * 8192;
  const Ctrl* c = ctrl + m;
  for (int i = t; i < 8192; i += 256) h[i] = 0;
  __syncthreads();
  unsigned vlo = c->vlo, sh = c->shift;
  for (int i = 0; i < 64; ++i) {
    int s = blockIdx.x * 64 + i;
    unsigned n = counts[s];
    const unsigned* seg = cbuf + (size_t)s * WAVE_CAP;
    for (unsigned k = t; k < n; k += 256)
      atomicAdd(&h[(seg[k] - vlo) >> sh], 1u);
  }
  if (blockIdx.x == 0) {
    unsigned nov = c->nov; if (nov > (unsigned)OVCAP) nov = OVCAP;
    for (unsigned k = t; k < nov; k += 256)
      atomicAdd(&h[(ovf[k] - vlo) >> sh], 1u);
  }
  __syncthreads();
  for (int i = t; i < 8192; i += 256)
    if (h[i]) atomicAdd(&gh[i], h[i]);
}

__global__ void k_sel_bin(const unsigned* __restrict__ gh_all, const unsigned* __restrict__ counts_all,
                          const unsigned* __restrict__ belows_all, Ctrl* __restrict__ ctrl) {
  __shared__ unsigned rb[256], rc[256];
  __shared__ unsigned cs[256];
  __shared__ unsigned pre[257];
  __shared__ int bsel[2];
  __shared__ unsigned pbase[2];
  __shared__ long long tot_below, tot_nin;
  int t = threadIdx.x, m = blockIdx.x;
  const unsigned* gh = gh_all + m * 8192;
  const unsigned* counts = counts_all + m * NSEG;
  const unsigned* belows = belows_all + m * NSEG;
  Ctrl* c = ctrl + m;
  unsigned bsum = 0, csum2 = 0;
  for (int i = 0; i < 16; ++i) { bsum += belows[t * 16 + i]; csum2 += counts[t * 16 + i]; }
  rb[t] = bsum; rc[t] = csum2;
  unsigned loc[32];
  unsigned s = 0;
  for (int i = 0; i < 32; ++i) { loc[i] = gh[t * 32 + i]; s += loc[i]; }
  cs[t] = s;
  __syncthreads();
  if (t == 0) {
    unsigned acc = 0;
    for (int i = 0; i < 256; ++i) { pre[i] = acc; acc += cs[i]; }
    pre[256] = acc;
    long long a = 0, b = 0;
    for (int i = 0; i < 256; ++i) { a += rb[i]; b += rc[i]; }
    unsigned nov = c->nov; if (nov > (unsigned)OVCAP) nov = OVCAP;
    tot_below = a; tot_nin = b + nov;
    bsel[0] = 0; bsel[1] = 0; pbase[0] = 0; pbase[1] = 0;
  }
  __syncthreads();
  long long nin = tot_nin;
  long long below = tot_below;
  for (int k = 0; k < 2; ++k) {
    long long r = (long long)(K0 + k) - below;
    if (r < 0) r = 0;
    if (r >= nin) r = nin - 1;
    if ((long long)pre[t] <= r && r < (long long)pre[t] + (long long)cs[t]) {
      unsigned acc = pre[t];
      for (int i = 0; i < 32; ++i) {
        if ((long long)(acc + loc[i]) > r) { bsel[k] = t * 32 + i; pbase[k] = acc; break; }
        acc += loc[i];
      }
    }
    __syncthreads();
  }
  if (t == 0) {
    int b0 = bsel[0], b1 = bsel[1];
    c->b0 = (unsigned)b0; c->b1 = (unsigned)b1;
    c->e_lo = c->vlo + ((unsigned)b0 << c->shift);
    c->e_hi = c->vlo + ((unsigned)(b1 + 1) << c->shift);
    c->base_e = (unsigned)(below + (long long)pbase[0]);
    c->nex = 0;
  }
}

__global__ void k_extract(const unsigned* __restrict__ cbuf_all, const unsigned* __restrict__ ovf_all,
                          const unsigned* __restrict__ counts_all, unsigned* __restrict__ ebuf_all,
                          Ctrl* __restrict__ ctrl) {
  int t = threadIdx.x, m = blockIdx.y;
  const unsigned* cbuf = cbuf_all + (size_t)m * NSEG * WAVE_CAP;
  const unsigned* ovf = ovf_all + (size_t)m * OVCAP;
  const unsigned* counts = counts_all + m * NSEG;
  unsigned* ebuf = ebuf_all + m * EBUF_CAP;
  Ctrl* c = ctrl + m;
  unsigned e_lo = c->e_lo, e_hi = c->e_hi;
  for (int i = 0; i < 64; ++i) {
    int s = blockIdx.x * 64 + i;
    unsigned n = counts[s];
    const unsigned* seg = cbuf + (size_t)s * WAVE_CAP;
    for (unsigned k = t; k < n; k += 256) {
      unsigned key = seg[k];
      if (key >= e_lo && key < e_hi) {
        unsigned p = atomicAdd(&c->nex, 1u);
        if (p < (unsigned)EBUF_CAP) ebuf[p] = key;
      }
    }
  }
  if (blockIdx.x == 0) {
    unsigned nov = c->nov; if (nov > (unsigned)OVCAP) nov = OVCAP;
    for (unsigned k = t; k < nov; k += 256) {
      unsigned key = ovf[k];
      if (key >= e_lo && key < e_hi) {
        unsigned p = atomicAdd(&c->nex, 1u);
        if (p < (unsigned)EBUF_CAP) ebuf[p] = key;
      }
    }
  }
}

__global__ void k_final(const unsigned* __restrict__ ebuf_all, Ctrl* __restrict__ ctrl,
                        double frac) {
  __shared__ unsigned keys[EBUF_CAP];
  __shared__ unsigned abits, bbits;
  int t = threadIdx.x, m = blockIdx.x;
  const unsigned* ebuf = ebuf_all + m * EBUF_CAP;
  Ctrl* c = ctrl + m;
  int n = (int)c->nex; if (n > EBUF_CAP) n = EBUF_CAP;
  for (int i = t; i < n; i += 256) keys[i] = ebuf[i];
  if (t == 0) { abits = 0; bbits = 0; }
  __syncthreads();
  long long r0 = (long long)K0 - (long long)c->base_e;
  long long r1 = r0 + 1;
  if (r0 < 0) r0 = 0; if (r0 > n - 1) r0 = n - 1;
  if (r1 < 0) r1 = 0; if (r1 > n - 1) r1 = n - 1;
  for (int i = t; i < n; i += 256) {
    unsigned k = keys[i];
    int cl = 0, ce = 0;
    for (int j = 0; j < n; ++j) {
      cl += (keys[j] < k) ? 1 : 0;
      ce += (keys[j] <= k) ? 1 : 0;
    }
    if ((long long)cl <= r0 && r0 < (long long)ce) abits = k;
    if ((long long)cl <= r1 && r1 < (long long)ce) bbits = k;
  }
  __syncthreads();
  if (t == 0) {
    double a = (double)__uint_as_float(abits);
    double b = (double)__uint_as_float(bbits);
    c->a = (float)a; c->b = (float)b;
    c->thr = (float)(a + frac * (b - a));
  }
}

// ---------------- compute pipeline ----------------

// relu(x) -> nine shifted 4x4 box sums (the pooled conv taps), bf16 out.
__global__ void k_pool(const float* __restrict__ x, __bf16* __restrict__ apool) {
  __shared__ float lds[4][1024];
  __shared__ float V[4][24][32];
  int t = threadIdx.x, wv = t >> 6, lane = t & 63;
  int p = blockIdx.x * 4 + wv;          // plane id: b*256 + c'
  int b = p >> 8, cch = p & 255;
  const float* xp = x + (size_t)p * 1024;
  for (int q = 0; q < 4; ++q) {
    float4 v = ((const float4*)xp)[q * 64 + lane];
    int idx = (q * 64 + lane) * 4;
    lds[wv][idx + 0] = fmaxf(v.x, 0.f);
    lds[wv][idx + 1] = fmaxf(v.y, 0.f);
    lds[wv][idx + 2] = fmaxf(v.z, 0.f);
    lds[wv][idx + 3] = fmaxf(v.w, 0.f);
  }
  __syncthreads();
  for (int e = lane; e < 768; e += 64) {
    int vi = e >> 5, ccol = e & 31;
    int i = vi / 3, dy = vi % 3;
    int r0 = 4 * i + dy - 1;
    float s = 0.f;
#pragma unroll
    for (int u = 0; u < 4; ++u) {
      int r = r0 + u;
      if (r >= 0 && r < 32) s += lds[wv][r * 32 + ccol];
    }
    V[wv][vi][ccol] = s;
  }
  __syncthreads();
  int pos = lane, i = pos >> 3, j = pos & 7;
  __bf16* ap = apool + (size_t)(b * 64 + pos) * KCONV + cch * 9;
#pragma unroll
  for (int dy = 0; dy < 3; ++dy) {
    int vi = i * 3 + dy;
#pragma unroll
    for (int dx = 0; dx < 3; ++dx) {
      int c0 = 4 * j + dx - 1;
      float s = 0.f;
#pragma unroll
      for (int v4 = 0; v4 < 4; ++v4) {
        int cc = c0 + v4;
        if (cc >= 0 && cc < 32) s += V[wv][vi][cc];
      }
      ap[dy * 3 + dx] = (__bf16)(s * 0.0625f);
    }
  }
}

// pooled conv as GEMM: nodes[b, c*64+pos] = sum_K conv_w[c,K] * apool[row,K]
__global__ void k_convgemm(const __bf16* __restrict__ apool, const float* __restrict__ cw,
                           __bf16* __restrict__ nodes) {
  int t = threadIdx.x, wv = t >> 6, l = t & 63;
  int cb = blockIdx.x & 15;        // 16-channel tile
  int rg = blockIdx.x >> 4;        // 256-row group
  int row0 = rg * 256 + wv * 64;
  int cbase = cb * 16;
  int kofs = (l >> 4) * 8;
  f32x4 acc[4] = {};
  const float* aw = cw + (size_t)(cbase + (l & 15)) * KCONV + kofs;
  for (int kk = 0; kk < KCONV; kk += 32) {
    float4 a0 = *(const float4*)(aw + kk);
    float4 a1 = *(const float4*)(aw + kk + 4);
    bf16x8 af;
    af[0] = (__bf16)a0.x; af[1] = (__bf16)a0.y; af[2] = (__bf16)a0.z; af[3] = (__bf16)a0.w;
    af[4] = (__bf16)a1.x; af[5] = (__bf16)a1.y; af[6] = (__bf16)a1.z; af[7] = (__bf16)a1.w;
#pragma unroll
    for (int rt = 0; rt < 4; ++rt) {
      const __bf16* bp = apool + (size_t)(row0 + rt * 16 + (l & 15)) * KCONV + kk + kofs;
      bf16x8 bv = *(const bf16x8*)bp;
      acc[rt] = __builtin_amdgcn_mfma_f32_16x16x32_bf16(af, bv, acc[rt], 0, 0, 0);
    }
  }
#pragma unroll
  for (int rt = 0; rt < 4; ++rt) {
    int prow = row0 + rt * 16 + (l & 15);
    int bidx = prow >> 6, pos = prow & 63;
#pragma unroll
    for (int j = 0; j < 4; ++j) {
      int cc = cbase + (l >> 4) * 4 + j;
      nodes[(size_t)bidx * NNODE + cc * 64 + pos] = (__bf16)acc[rt][j];
    }
  }
}

// hf_part[ks][f*32+b] = partial over K chunk ks (plain stores, no atomics)
__global__ void k_gemm1(const float* __restrict__ w1, const __bf16* __restrict__ nodes,
                        const Ctrl* __restrict__ ctrl, float* __restrict__ hfp) {
  int t = threadIdx.x, wv = t >> 6, l = t & 63;
  int fb = blockIdx.x >> 5;        // 32 feature blocks of 64
  int ks = blockIdx.x & 31;        // K chunk of 512
  float thr = ctrl->thr;
  int kofs = (l >> 4) * 8;
  int kk0 = ks * 512;
  const float*  awp = w1 + (size_t)(fb * 64 + wv * 16 + (l & 15)) * NNODE + kk0 + kofs;
  const __bf16* b0p = nodes + (size_t)(l & 15) * NNODE + kk0 + kofs;
  const __bf16* b1p = nodes + (size_t)((l & 15) + 16) * NNODE + kk0 + kofs;
  f32x4 acc0 = {}, acc1 = {};
#pragma unroll 4
  for (int kk = 0; kk < 512; kk += 32) {
    float4 a0 = *(const float4*)(awp + kk);
    float4 a1 = *(const float4*)(awp + kk + 4);
    bf16x8 af;
    af[0] = (__bf16)prune1(a0.x, thr); af[1] = (__bf16)prune1(a0.y, thr);
    af[2] = (__bf16)prune1(a0.z, thr); af[3] = (__bf16)prune1(a0.w, thr);
    af[4] = (__bf16)prune1(a1.x, thr); af[5] = (__bf16)prune1(a1.y, thr);
    af[6] = (__bf16)prune1(a1.z, thr); af[7] = (__bf16)prune1(a1.w, thr);
    bf16x8 bv0 = *(const bf16x8*)(b0p + kk);
    bf16x8 bv1 = *(const bf16x8*)(b1p + kk);
    acc0 = __builtin_amdgcn_mfma_f32_16x16x32_bf16(af, bv0, acc0, 0, 0, 0);
    acc1 = __builtin_amdgcn_mfma_f32_16x16x32_bf16(af, bv1, acc1, 0, 0, 0);
  }
  float* dst = hfp + (size_t)ks * 65536;
#pragma unroll
  for (int j = 0; j < 4; ++j) {
    int f = fb * 64 + wv * 16 + (l >> 4) * 4 + j;
    dst[f * 32 + (l & 15)] = acc0[j];
    dst[f * 32 + 16 + (l & 15)] = acc1[j];
  }
}

// reduce 32 partials + relu + transpose + bf16
__global__ void k_relucvt(const float* __restrict__ hfp, __bf16* __restrict__ hb) {
  int idx = blockIdx.x * 256 + threadIdx.x;   // 65536 = f*32+b
  float s = 0.f;
#pragma unroll
  for (int ks = 0; ks < 32; ++ks) s += hfp[(size_t)ks * 65536 + idx];
  float v = fmaxf(s, 0.f);
  int f = idx >> 5, b = idx & 31;
  hb[b * FEATD + f] = (__bf16)v;
}

// g_part[ks][n*32+b] partials (plain stores)
__global__ void k_gemm2(const float* __restrict__ w2, const __bf16* __restrict__ hb,
                        const Ctrl* __restrict__ ctrl, float* __restrict__ gp) {
  int t = threadIdx.x, wv = t >> 6, l = t & 63;
  int nb = blockIdx.x >> 2;        // 256 row blocks of 64
  int ks = blockIdx.x & 3;         // K chunk of 512
  float thr = ctrl->thr;
  int kofs = (l >> 4) * 8;
  int kk0 = ks * 512;
  const float*  awp = w2 + (size_t)(nb * 64 + wv * 16 + (l & 15)) * FEATD + kk0 + kofs;
  const __bf16* b0p = hb + (size_t)(l & 15) * FEATD + kk0 + kofs;
  const __bf16* b1p = hb + (size_t)((l & 15) + 16) * FEATD + kk0 + kofs;
  f32x4 acc0 = {}, acc1 = {};
#pragma unroll 4
  for (int kk = 0; kk < 512; kk += 32) {
    float4 a0 = *(const float4*)(awp + kk);
    float4 a1 = *(const float4*)(awp + kk + 4);
    bf16x8 af;
    af[0] = (__bf16)prune1(a0.x, thr); af[1] = (__bf16)prune1(a0.y, thr);
    af[2] = (__bf16)prune1(a0.z, thr); af[3] = (__bf16)prune1(a0.w, thr);
    af[4] = (__bf16)prune1(a1.x, thr); af[5] = (__bf16)prune1(a1.y, thr);
    af[6] = (__bf16)prune1(a1.z, thr); af[7] = (__bf16)prune1(a1.w, thr);
    bf16x8 bv0 = *(const bf16x8*)(b0p + kk);
    bf16x8 bv1 = *(const bf16x8*)(b1p + kk);
    acc0 = __builtin_amdgcn_mfma_f32_16x16x32_bf16(af, bv0, acc0, 0, 0, 0);
    acc1 = __builtin_amdgcn_mfma_f32_16x16x32_bf16(af, bv1, acc1, 0, 0, 0);
  }
  float* dst = gp + (size_t)ks * 524288;
#pragma unroll
  for (int j = 0; j < 4; ++j) {
    int n = nb * 64 + wv * 16 + (l >> 4) * 4 + j;
    dst[n * 32 + (l & 15)] = acc0[j];
    dst[n * 32 + 16 + (l & 15)] = acc1[j];
  }
}

// reduce 4 partials + instance norm on the 8x8 grid + 4x upsample
__global__ void k_normup(const float* __restrict__ gp, const float* __restrict__ gamma,
                         const float* __restrict__ beta, float* __restrict__ out) {
  int t = threadIdx.x, wv = t >> 6, lane = t & 63;
  int id = blockIdx.x * 4 + wv;         // b*256 + c
  int b = id >> 8, cch = id & 255;
  size_t gi = (size_t)(cch * 64 + lane) * 32 + b;
  float v = gp[gi] + gp[gi + 524288] + gp[gi + 2 * 524288] + gp[gi + 3 * 524288];
  float s = v;
  for (int off = 1; off < 64; off <<= 1) s += __shfl_xor(s, off);
  float mean = s * (1.0f / 64.0f);
  float d = v - mean;
  float q = d * d;
  for (int off = 1; off < 64; off <<= 1) q += __shfl_xor(q, off);
  float var = q * (1.0f / 64.0f);
  float y = d * rsqrtf(var + 1e-5f) * gamma[cch] + beta[cch];
  int i = lane >> 3, j = lane & 7;
  float4 y4 = { y, y, y, y };
  float* op = out + ((size_t)(b * 256 + cch) * 32 + i * 4) * 32 + j * 4;
#pragma unroll
  for (int u = 0; u < 4; ++u) *(float4*)(op + u * 32) = y4;
}

// ---------------------------------------------------------------------------

extern "C" void kernel_launch(void* const* d_in, const int* in_sizes, int n_in,
                              void* d_out, int out_size, void* d_ws, size_t ws_size,
                              hipStream_t stream) {
  const float* x      = (const float*)d_in[0];
  const float* conv_w = (const float*)d_in[1];
  const float* w1     = (const float*)d_in[2];
  const float* w2     = (const float*)d_in[3];
  const float* gamma  = (const float*)d_in[4];
  const float* beta   = (const float*)d_in[5];
  float* out = (float*)d_out;

  if (ws_size < WS_MIN) return;   // fail loudly via wrong output

  char* wsb = (char*)d_ws;
  __bf16*   apool  = (__bf16*)(wsb + OFF_APOOL);
  __bf16*   nodes  = (__bf16*)(wsb + OFF_NODES);
  float*    hfp    = (float*)(wsb + OFF_HFP);
  __bf16*   hb     = (__bf16*)(wsb + OFF_HB);
  float*    gp     = (float*)(wsb + OFF_GP);
  unsigned* shist  = (unsigned*)(wsb + OFF_SHIST);
  unsigned* ghist  = (unsigned*)(wsb + OFF_GHIST);
  Ctrl*     ctrl   = (Ctrl*)(wsb + OFF_CTRL);
  unsigned* ebuf   = (unsigned*)(wsb + OFF_EBUF);
  unsigned* counts = (unsigned*)(wsb + OFF_CNT);
  unsigned* belows = (unsigned*)(wsb + OFF_BLW);
  unsigned* cbuf   = (unsigned*)(wsb + OFF_CBUF);
  unsigned* ovf    = (unsigned*)(wsb + OFF_OVF);

  const double frac = POS_D - (double)K0;

  // one fill for both matrices' coarse + fine histograms (contiguous)
  hipMemsetAsync(shist, 0, (OFF_CTRL - OFF_SHIST), stream);

  k_sample_hist<<<dim3(512, 2), 256, 0, stream>>>(w1, w2, shist);
  k_range2<<<2, 256, 0, stream>>>(shist, ctrl);
  k_compact<<<dim3(1024, 2), 256, 0, stream>>>(w1, w2, cbuf, ovf, counts, belows, ctrl);
  k_sel_hist<<<dim3(64, 2), 256, 0, stream>>>(cbuf, ovf, counts, ghist, ctrl);
  k_sel_bin<<<2, 256, 0, stream>>>(ghist, counts, belows, ctrl);
  k_extract<<<dim3(64, 2), 256, 0, stream>>>(cbuf, ovf, counts, ebuf, ctrl);
  k_final<<<2, 256, 0, stream>>>(ebuf, ctrl, frac);

  k_pool<<<2048, 256, 0, stream>>>(x, apool);
  k_convgemm<<<128, 256, 0, stream>>>(apool, conv_w, nodes);

  k_gemm1<<<1024, 256, 0, stream>>>(w1, nodes, ctrl + 0, hfp);
  k_relucvt<<<256, 256, 0, stream>>>(hfp, hb);

  k_gemm2<<<1024, 256, 0, stream>>>(w2, hb, ctrl + 1, gp);

  k_normup<<<2048, 256, 0, stream>>>(gp, gamma, beta, out);
}